// Round 8
// baseline (180.034 us; speedup 1.0000x reference)
//
#include <hip/hip_runtime.h>

typedef __bf16 bf16;
typedef __attribute__((ext_vector_type(8))) __bf16 bf16x8;
typedef __attribute__((ext_vector_type(4))) __bf16 bf16x4;
typedef __attribute__((ext_vector_type(4))) float f32x4;

__device__ __forceinline__ void gload16(const void* g, void* l) {
  __builtin_amdgcn_global_load_lds(
      (__attribute__((address_space(1))) void*)(g),
      (__attribute__((address_space(3))) void*)(l), 16, 0, 0);
}

// ---------------------------------------------------------------------------
// Workspace layout (bytes):
//   xh  : NHWC padded input, bf16 [130][130][512]        = 17,305,600
//   w1t : conv1 weights,     bf16 [9][512 oc][512 c]     =  4,718,592
//   w2p : packed head wts,   bf16 [80 oc2][512 c]        =     81,920
//   mid : conv1 output NHWC, bf16 [16384 px][512 oc]     = 16,777,216
// ---------------------------------------------------------------------------
#define WS_XH   0
#define WS_W1T  17305600
#define WS_W2P  22024192
#define WS_MID  22106112

#define OUT_CLS 786432
#define OUT_ROI 1179648

// ---------------- fused prep: border | w1 repack | w2 pack | transpose -----
// grid = 132 + 1024 + 160 + 2048 = 3364 blocks, 256 thr    (unchanged)
__global__ void prep_all(int4* __restrict__ xh4,
                         const float* __restrict__ w1, bf16* __restrict__ w1t,
                         const float* __restrict__ loc_w,
                         const float* __restrict__ score_w,
                         bf16* __restrict__ w2p,
                         const float* __restrict__ x, bf16* __restrict__ xh) {
  __shared__ float lds[64][65];
  float* ldsf = &lds[0][0];
  const int t = threadIdx.x;
  const int b = blockIdx.x;
  if (b < 132) {                       // ---- xh halo border zeroing
    const int4 z = make_int4(0, 0, 0, 0);
    if (b < 130) {
      if (t < 64)       xh4[(b * 130 + 0) * 64 + t] = z;
      else if (t < 128) xh4[(b * 130 + 129) * 64 + (t - 64)] = z;
    } else {
      const int r = (b == 130) ? 0 : 129;
      for (int i = t; i < 8320; i += 256) xh4[r * 8320 + i] = z;
    }
  } else if (b < 1156) {               // ---- w1 [oc][c][3][3] -> w1t[j][oc][c]
    const int bb = b - 132;
    const long base = (long)bb * 2304;
#pragma unroll
    for (int i = 0; i < 9; ++i) ldsf[i * 256 + t] = w1[base + i * 256 + t];
    __syncthreads();
    const int pair0 = bb * 256;        // pair = oc*512 + c
#pragma unroll
    for (int j = 0; j < 9; ++j)
      w1t[(long)j * 262144 + pair0 + t] = (bf16)ldsf[t * 9 + j];
  } else if (b < 1316) {               // ---- pack loc_w+score_w -> w2p[80][512]
    const int idx = (b - 1156) * 256 + t;
    const int c  = idx & 511;
    const int oc = idx >> 9;
    float v = 0.f;
    if (oc < 48)      v = loc_w[oc * 512 + c];
    else if (oc < 72) v = score_w[(oc - 48) * 512 + c];
    w2p[idx] = (bf16)v;
  } else {                             // ---- NCHW fp32 -> NHWC bf16 transpose
    const int bb   = b - 1316;
    const int ct   = bb & 7;
    const int colt = (bb >> 3) & 1;
    const int r    = 1 + (bb >> 4);
    const int c0   = ct * 64;
    const int col0 = 1 + colt * 64;
    const int lcol = t & 63;
    const int coff = t >> 6;
#pragma unroll
    for (int i = 0; i < 16; ++i) {
      const int cl = coff + i * 4;
      lds[cl][lcol] = x[(long)(c0 + cl) * 16384 + (r - 1) * 128 + (col0 - 1) + lcol];
    }
    __syncthreads();
#pragma unroll
    for (int i = 0; i < 2; ++i) {
      const int idx = i * 256 + t;
      const int pxl = idx >> 3;
      const int oct = idx & 7;
      bf16x8 v;
#pragma unroll
      for (int e = 0; e < 8; ++e) v[e] = (bf16)lds[oct * 8 + e][pxl];
      *(bf16x8*)(xh + (long)(r * 130 + col0 + pxl) * 512 + c0 + oct * 8) = v;
    }
  }
}

// ---------------- conv1 implicit GEMM: m201-skeleton phases ----------------
// R1-R7 accounting: every hand-rolled schedule lands at subslot ~= LDS
// content + MFMA content SERIAL (MFMA blocks its wave; my pipelines never
// engage). Port the measured-62%-MfmaUtil structure instead (guide m201,
// same 8-reads/16-MFMA-per-wave content ratio): per subslot
//   {ds_read frags; issue stage loads; role-based counted vmcnt;
//    s_barrier; lgkmcnt(0)+sched_barrier; setprio(1); 16 MFMA; setprio(0);
//    s_barrier}
// with 8 dual-role waves (2/SIMD). m201's 825cy/phase (620 MFMA + ~205
// read-drain for 48KB) shows multi-wave LDS drain runs ~230B/cy, so the
// separated read phase costs ~270cy for our 64KB, not the single-wave
// 770cy I'd modeled. Traffic design unchanged from R5 (64oc x 512px
// blocks, ocT=b&7 XCD-pinned A, 9-tap-shared B window, ping/pong).
// Sync proof: waits precede B1(t); reads(t+1) follow B2(t). A ring-4
// staged 3 ahead, A-waves vmcnt(2) (drains exactly A(t+1), keeps 2 in
// flight); B-waves vmcnt(0) only at j==8 (pong loads issued <= j==5).
// WAR: slot (t+3)&3 written at t, last read at t-1 before B2(t-1); pong
// written s while ping read; frag regs protected by register dataflow.
__global__ __launch_bounds__(512, 1) void conv1_gemm(
    const bf16* __restrict__ w1t, const bf16* __restrict__ xh,
    const float* __restrict__ b1, bf16* __restrict__ mid) {
  extern __shared__ char smem[];
  // B ping [784 rows][64B] @ 0 ; B pong @ 50176 ; A ring 4x4KB @ 100352
  char* Bb0 = smem;
  char* Bb1 = smem + 50176;
  char* Ab  = smem + 100352;          // total 116736 B

  const int tid  = threadIdx.x;
  const int wave = tid >> 6;
  const int lane = tid & 63;
  const int quad = lane >> 4;
  const int l15  = lane & 15;
  const int b    = blockIdx.x;
  const int ocT  = b & 7;          // XCD-affine: same ocT -> same XCD L2
  const int r4   = b >> 3;         // 4-image-row px tile, 0..31
  const long rbase = (long)r4 * 520;        // 4*130 xh rows per tile

  const char* w1tB = (const char*)w1t + (long)ocT * 65536;
  const char* xhB  = (const char*)xh;

  const int srow = lane >> 2;                               // 16 rows/unit
  const int schk = ((lane & 3) ^ ((lane >> 3) & 3)) << 4;   // src chunk swizzle
  const int si   = wave - 4;                                // B-stager idx

  // A-wave w (0..3) stages rows [w*16,+16) of tile (tap,ck) into ring slot
  auto stageA = [&](int ck, int tap, int slot) {
    const char* src = w1tB + (long)tap * 524288 +
                      (long)(wave * 16 + srow) * 1024 + ck * 64 + schk;
    gload16(src, Ab + slot * 4096 + wave * 1024);
  };
  // stage 1KB unit u (16 xh rows) of the B window at column ck
  auto stageB = [&](int ck, int u, char* Bt) {
    const char* src = xhB + (rbase + u * 16 + srow) * 1024 + ck * 64 + schk;
    gload16(src, Bt + u * 1024);
  };

  // wave owns px [wave*64, +64): B row bases (R1-verified mapping)
  const int p0 = wave * 64;
  const int rowb0 = (((p0 + 0)  >> 7) * 130) + ((p0 + 0)  & 127) + l15;
  const int rowb1 = (((p0 + 16) >> 7) * 130) + ((p0 + 16) & 127) + l15;
  const int rowb2 = (((p0 + 32) >> 7) * 130) + ((p0 + 32) & 127) + l15;
  const int rowb3 = (((p0 + 48) >> 7) * 130) + ((p0 + 48) & 127) + l15;
  const int aoff = l15 * 64 + ((quad ^ ((l15 >> 1) & 3)) << 4);

  f32x4 acc[4][4];
#pragma unroll
  for (int i = 0; i < 4; ++i)
#pragma unroll
    for (int k = 0; k < 4; ++k) acc[i][k] = (f32x4){0.f, 0.f, 0.f, 0.f};

  bf16x8 af0, af1, af2, af3, bf0, bf1, bf2, bf3;

#define BROW(R, BT) (*(const bf16x8*)((BT) + (R) * 64 + ((quad ^ (((R) >> 1) & 3)) << 4)))
#define READF(SLOT, KO, BT)                                                   \
  do {                                                                        \
    const char* _ab = Ab + (SLOT) * 4096 + aoff;                              \
    af0 = *(const bf16x8*)(_ab);                                              \
    af1 = *(const bf16x8*)(_ab + 1024);                                       \
    af2 = *(const bf16x8*)(_ab + 2048);                                       \
    af3 = *(const bf16x8*)(_ab + 3072);                                       \
    const int _r0 = rowb0 + (KO);                                             \
    const int _r1 = rowb1 + (KO);                                             \
    const int _r2 = rowb2 + (KO);                                             \
    const int _r3 = rowb3 + (KO);                                             \
    bf0 = BROW(_r0, BT); bf1 = BROW(_r1, BT);                                 \
    bf2 = BROW(_r2, BT); bf3 = BROW(_r3, BT);                                 \
  } while (0)
#define MF(MI, NI, AF, BF)                                                    \
  acc[MI][NI] = __builtin_amdgcn_mfma_f32_16x16x32_bf16(AF, BF, acc[MI][NI], 0, 0, 0)
#define MFMA16()                                                              \
  do {                                                                        \
    __builtin_amdgcn_s_setprio(1);                                            \
    MF(0, 0, af0, bf0); MF(0, 1, af0, bf1); MF(0, 2, af0, bf2); MF(0, 3, af0, bf3); \
    MF(1, 0, af1, bf0); MF(1, 1, af1, bf1); MF(1, 2, af1, bf2); MF(1, 3, af1, bf3); \
    MF(2, 0, af2, bf0); MF(2, 1, af2, bf1); MF(2, 2, af2, bf2); MF(2, 3, af2, bf3); \
    MF(3, 0, af3, bf0); MF(3, 1, af3, bf1); MF(3, 2, af3, bf2); MF(3, 3, af3, bf3); \
    __builtin_amdgcn_s_setprio(0);                                            \
  } while (0)

#define KOFF(J) (((J) / 3) * 130 + ((J) % 3))
#define WAITA2 asm volatile("s_waitcnt vmcnt(2)" ::: "memory")
#define WAITA1 asm volatile("s_waitcnt vmcnt(1)" ::: "memory")
#define WAIT0  asm volatile("s_waitcnt vmcnt(0)" ::: "memory")
#define BARR   __builtin_amdgcn_s_barrier()
#define SB     __builtin_amdgcn_sched_barrier(0)
#define LGKM0  do { asm volatile("s_waitcnt lgkmcnt(0)" ::: "memory"); SB; } while (0)
// one subslot: reads -> stage -> wait -> B1 -> lgkm0 -> MFMA -> B2
#define PHASE_TAIL()                                                          \
  do { SB; BARR; LGKM0; MFMA16(); BARR; } while (0)

  // prologue: B ping fully; A tiles for t=0,1,2 into ring slots 0,1,2
  if (wave < 4) {
    stageA(0, 0, 0); stageA(0, 1, 1); stageA(0, 2, 2);
  } else {
    const int u0 = (si == 0) ? 0 : 13 + (si - 1) * 12;
    const int n  = (si == 0) ? 13 : 12;
    for (int u = 0; u < n; ++u) stageB(0, u0 + u, Bb0);
  }
  WAIT0;
  BARR;

#pragma unroll 1
  for (int s = 0; s < 15; ++s) {
    char* Bcur = (s & 1) ? Bb1 : Bb0;
    char* Bnxt = (s & 1) ? Bb0 : Bb1;
#pragma unroll
    for (int j = 0; j < 9; ++j) {
      READF((s + j) & 3, KOFF(j), Bcur);
      if (wave < 4) {                   // A: stage tile t+3 into ring
        if (j < 6) stageA(s, j + 3, (s + j + 3) & 3);
        else       stageA(s + 1, j - 6, (s + j + 3) & 3);
        WAITA2;                         // drains exactly A(t+1)
      } else {                          // B: ~2 pong units on j=0..5
        if (j < 6) {
          const int n  = (si == 0 && j == 0) ? 3 : 2;
          const int u0 = (si == 0) ? ((j == 0) ? 0 : 3 + (j - 1) * 2)
                                   : (13 + (si - 1) * 12 + j * 2);
          for (int u = 0; u < n; ++u) stageB(s + 1, u0 + u, Bnxt);
        }
        if (j == 8) { WAIT0; }          // pong certified for next superslot
      }
      PHASE_TAIL();
    }
  }
  { // s = 15 peel: no B staging; exact A drain
#pragma unroll
    for (int j = 0; j < 9; ++j) {
      READF((15 + j) & 3, KOFF(j), Bb1);
      if (wave < 4) {
        if (j < 6)      { stageA(15, j + 3, (15 + j + 3) & 3); WAITA2; }
        else if (j == 6) { WAITA1; }    // certify A(142)
        else if (j == 7) { WAIT0; }     // certify A(143)
      }
      PHASE_TAIL();
    }
  }

#undef KOFF
#undef WAITA2
#undef WAITA1
#undef WAIT0
#undef BARR
#undef SB
#undef LGKM0
#undef PHASE_TAIL
#undef BROW
#undef READF
#undef MF
#undef MFMA16

  // epilogue: bias + relu, store bf16 NHWC mid[px][oc]
#pragma unroll
  for (int mi = 0; mi < 4; ++mi) {
    const int oc = ocT * 64 + mi * 16 + quad * 4;
    const float bv0 = b1[oc], bv1 = b1[oc + 1], bv2 = b1[oc + 2], bv3 = b1[oc + 3];
#pragma unroll
    for (int ni = 0; ni < 4; ++ni) {
      const int pb  = p0 + ni * 16;
      const int gpx = (r4 * 4 + (pb >> 7)) * 128 + (pb & 127) + l15;
      f32x4 a = acc[mi][ni];
      float t0 = a[0] + bv0; t0 = t0 > 0.f ? t0 : 0.f;
      float t1 = a[1] + bv1; t1 = t1 > 0.f ? t1 : 0.f;
      float t2 = a[2] + bv2; t2 = t2 > 0.f ? t2 : 0.f;
      float t3 = a[3] + bv3; t3 = t3 > 0.f ? t3 : 0.f;
      bf16x4 v = {(bf16)t0, (bf16)t1, (bf16)t2, (bf16)t3};
      *(bf16x4*)(mid + (long)gpx * 512 + oc) = v;
    }
  }
}

// ---------------- head: barrier-free K-split GEMM + anchor decode ----------
__global__ __launch_bounds__(256) void head_gemm(
    const bf16* __restrict__ w2p, const bf16* __restrict__ mid,
    const float* __restrict__ loc_b, const float* __restrict__ score_b,
    float* __restrict__ out) {
  __shared__ f32x4 red[3][64][5];
  const int tid  = threadIdx.x;
  const int wave = tid >> 6;
  const int lane = tid & 63;
  const int quad = lane >> 4;
  const int l15  = lane & 15;
  const int px0  = blockIdx.x * 16;
  const bf16* mB = mid + (long)px0 * 512;

  f32x4 acc[5];
#pragma unroll
  for (int i = 0; i < 5; ++i) acc[i] = (f32x4){0.f, 0.f, 0.f, 0.f};

#pragma unroll
  for (int st = 0; st < 4; ++st) {
    const int k0 = wave * 128 + st * 32;
    bf16x8 bfr = *(const bf16x8*)(mB + (long)l15 * 512 + k0 + quad * 8);
#pragma unroll
    for (int mi = 0; mi < 5; ++mi) {
      bf16x8 af = *(const bf16x8*)(w2p + (long)(mi * 16 + l15) * 512 + k0 + quad * 8);
      acc[mi] = __builtin_amdgcn_mfma_f32_16x16x32_bf16(af, bfr, acc[mi], 0, 0, 0);
    }
  }

  if (wave > 0) {
#pragma unroll
    for (int mi = 0; mi < 5; ++mi) red[wave - 1][lane][mi] = acc[mi];
  }
  __syncthreads();
  if (wave != 0) return;
#pragma unroll
  for (int w = 0; w < 3; ++w)
#pragma unroll
    for (int mi = 0; mi < 5; ++mi) acc[mi] += red[w][lane][mi];

  const int p    = px0 + l15;
  const int hh   = p >> 7;
  const int wcol = p & 127;
  const float cx = 16.f * (float)hh;
  const float cy = 16.f * (float)wcol;
  const float s0 = quad == 0 ? 45.f : quad == 1 ? 91.f : quad == 2 ? 181.f : 362.f;
  const float s1 = quad == 0 ? 32.f : quad == 1 ? 64.f : quad == 2 ? 128.f : 256.f;
  const float s2 = quad == 0 ? 23.f : quad == 1 ? 45.f : quad == 2 ? 91.f : 181.f;
  const float aw[3] = {s0, s1, s2};
  const float ah[3] = {s2, s1, s0};
#pragma unroll
  for (int mi = 0; mi < 5; ++mi) {
#pragma unroll
    for (int r = 0; r < 4; ++r) {
      const int oc2 = mi * 16 + quad * 4 + r;
      float v = acc[mi][r];
      if (mi < 3) {
        v += loc_b[oc2];
        out[p * 48 + oc2] = v;
        float roi;
        if (r == 0)      roi = v * aw[mi] + cx;
        else if (r == 1) roi = v * ah[mi] + cy;
        else if (r == 2) roi = __expf(v) * aw[mi];
        else             roi = __expf(v) * ah[mi];
        out[OUT_ROI + p * 48 + oc2] = roi;
      } else {
        const int sc = oc2 - 48;
        if (sc < 24) {
          v += score_b[sc];
          out[OUT_CLS + p * 24 + sc] = v;
        }
      }
    }
  }
}

// ---------------------------------------------------------------------------
extern "C" void kernel_launch(void* const* d_in, const int* in_sizes, int n_in,
                              void* d_out, int out_size, void* d_ws, size_t ws_size,
                              hipStream_t stream) {
  (void)in_sizes; (void)n_in; (void)out_size; (void)ws_size;
  const float* x       = (const float*)d_in[0];
  const float* conv1_w = (const float*)d_in[1];
  const float* conv1_b = (const float*)d_in[2];
  const float* score_w = (const float*)d_in[3];
  const float* score_b = (const float*)d_in[4];
  const float* loc_w   = (const float*)d_in[5];
  const float* loc_b   = (const float*)d_in[6];
  char* ws = (char*)d_ws;
  bf16* xh  = (bf16*)(ws + WS_XH);
  bf16* w1t = (bf16*)(ws + WS_W1T);
  bf16* w2p = (bf16*)(ws + WS_W2P);
  bf16* mid = (bf16*)(ws + WS_MID);
  float* out = (float*)d_out;

  static int attr_done = 0;
  if (!attr_done) {
    (void)hipFuncSetAttribute((const void*)conv1_gemm,
                              hipFuncAttributeMaxDynamicSharedMemorySize, 116736);
    attr_done = 1;
  }

  hipLaunchKernelGGL(prep_all,   dim3(3364), dim3(256), 0, stream,
                     (int4*)xh, conv1_w, w1t, loc_w, score_w, w2p, x, xh);
  hipLaunchKernelGGL(conv1_gemm, dim3(256),  dim3(512), 116736, stream,
                     w1t, xh, conv1_b, mid);
  hipLaunchKernelGGL(head_gemm,  dim3(1024), dim3(256), 0, stream,
                     w2p, mid, loc_b, score_b, out);
}

// Round 9
// 177.448 us; speedup vs baseline: 1.0146x; 1.0146x over previous
//
#include <hip/hip_runtime.h>

typedef __bf16 bf16;
typedef __attribute__((ext_vector_type(8))) __bf16 bf16x8;
typedef __attribute__((ext_vector_type(4))) __bf16 bf16x4;
typedef __attribute__((ext_vector_type(4))) float f32x4;

__device__ __forceinline__ void gload16(const void* g, void* l) {
  __builtin_amdgcn_global_load_lds(
      (__attribute__((address_space(1))) void*)(g),
      (__attribute__((address_space(3))) void*)(l), 16, 0, 0);
}

// ---------------------------------------------------------------------------
// Workspace layout (bytes):
//   xh  : NHWC padded input, bf16 [130][130][512]        = 17,305,600
//   w1t : conv1 weights,     bf16 [9][512 oc][512 c]     =  4,718,592
//   w2p : packed head wts,   bf16 [80 oc2][512 c]        =     81,920
//   mid : conv1 output NHWC, bf16 [16384 px][512 oc]     = 16,777,216
// ---------------------------------------------------------------------------
#define WS_XH   0
#define WS_W1T  17305600
#define WS_W2P  22024192
#define WS_MID  22106112

#define OUT_CLS 786432
#define OUT_ROI 1179648

// ---------------- fused prep: border | w1 repack | w2 pack | transpose -----
// grid = 132 + 1024 + 160 + 2048 = 3364 blocks, 256 thr    (unchanged)
__global__ void prep_all(int4* __restrict__ xh4,
                         const float* __restrict__ w1, bf16* __restrict__ w1t,
                         const float* __restrict__ loc_w,
                         const float* __restrict__ score_w,
                         bf16* __restrict__ w2p,
                         const float* __restrict__ x, bf16* __restrict__ xh) {
  __shared__ float lds[64][65];
  float* ldsf = &lds[0][0];
  const int t = threadIdx.x;
  const int b = blockIdx.x;
  if (b < 132) {                       // ---- xh halo border zeroing
    const int4 z = make_int4(0, 0, 0, 0);
    if (b < 130) {
      if (t < 64)       xh4[(b * 130 + 0) * 64 + t] = z;
      else if (t < 128) xh4[(b * 130 + 129) * 64 + (t - 64)] = z;
    } else {
      const int r = (b == 130) ? 0 : 129;
      for (int i = t; i < 8320; i += 256) xh4[r * 8320 + i] = z;
    }
  } else if (b < 1156) {               // ---- w1 [oc][c][3][3] -> w1t[j][oc][c]
    const int bb = b - 132;
    const long base = (long)bb * 2304;
#pragma unroll
    for (int i = 0; i < 9; ++i) ldsf[i * 256 + t] = w1[base + i * 256 + t];
    __syncthreads();
    const int pair0 = bb * 256;        // pair = oc*512 + c
#pragma unroll
    for (int j = 0; j < 9; ++j)
      w1t[(long)j * 262144 + pair0 + t] = (bf16)ldsf[t * 9 + j];
  } else if (b < 1316) {               // ---- pack loc_w+score_w -> w2p[80][512]
    const int idx = (b - 1156) * 256 + t;
    const int c  = idx & 511;
    const int oc = idx >> 9;
    float v = 0.f;
    if (oc < 48)      v = loc_w[oc * 512 + c];
    else if (oc < 72) v = score_w[(oc - 48) * 512 + c];
    w2p[idx] = (bf16)v;
  } else {                             // ---- NCHW fp32 -> NHWC bf16 transpose
    const int bb   = b - 1316;
    const int ct   = bb & 7;
    const int colt = (bb >> 3) & 1;
    const int r    = 1 + (bb >> 4);
    const int c0   = ct * 64;
    const int col0 = 1 + colt * 64;
    const int lcol = t & 63;
    const int coff = t >> 6;
#pragma unroll
    for (int i = 0; i < 16; ++i) {
      const int cl = coff + i * 4;
      lds[cl][lcol] = x[(long)(c0 + cl) * 16384 + (r - 1) * 128 + (col0 - 1) + lcol];
    }
    __syncthreads();
#pragma unroll
    for (int i = 0; i < 2; ++i) {
      const int idx = i * 256 + t;
      const int pxl = idx >> 3;
      const int oct = idx & 7;
      bf16x8 v;
#pragma unroll
      for (int e = 0; e < 8; ++e) v[e] = (bf16)lds[oct * 8 + e][pxl];
      *(bf16x8*)(xh + (long)(r * 130 + col0 + pxl) * 512 + c0 + oct * 8) = v;
    }
  }
}

// ---------------- conv1 implicit GEMM: wave-specialized + 2-deep pipe ------
// Base = R7 (best, 76us): waves 0-3 pure compute (64oc x 128px, acc 4x8),
// waves 4-7 pure stagers (counted vmcnt, certify at 1 barrier/group).
// R7's residual: reads for half h+1 issued only ~130cy before use (after
// MFMA(h) in program order) while the CU LDS pipe (4 waves x 8 reads)
// needs ~290-380cy -> every half stalls on lgkm; subslot = LDS + MFMA
// summed. R8 (m201 2-barrier skeleton) regressed: re-lockstepped waves.
// This version: PREFETCH DISTANCE 2 HALVES. 3 rotating B register sets +
// 2 A sets; reads for half h+2 issue before MFMA(h), pinned by
// sched_barrier(0). Compiler then emits counted lgkmcnt(12) (it tracks
// outstanding ds_reads exactly) so prefetched reads fly across MFMA
// clusters -> ~516cy cover vs ~384cy pipe demand. All prefetches stay
// inside the group certified at the group barrier: R7's staging schedule,
// counted vmcnt waits, and WAR distances carry over VERBATIM.
// Regs: acc 128 AGPR + 20 bf16x8 frags (80) + addr ~30 => ~252/256 at
// 2 waves/SIMD. Health check in counters: VGPR ~120-130, WRITE ~16.5MB.
__global__ __launch_bounds__(512, 1) void conv1_gemm(
    const bf16* __restrict__ w1t, const bf16* __restrict__ xh,
    const float* __restrict__ b1, bf16* __restrict__ mid) {
  extern __shared__ char smem[];
  // B ping [784 rows][64B] @ 0 ; B pong @ 50176 ; A taps 9x4KB @ 100352
  char* Bb0 = smem;
  char* Bb1 = smem + 50176;
  char* Ab  = smem + 100352;          // total 137216 B

  const int tid  = threadIdx.x;
  const int wave = tid >> 6;
  const int lane = tid & 63;
  const int quad = lane >> 4;
  const int l15  = lane & 15;
  const int b    = blockIdx.x;
  const int ocT  = b & 7;          // XCD-affine: same ocT -> same XCD L2
  const int r4   = b >> 3;         // 4-image-row px tile, 0..31
  const long rbase = (long)r4 * 520;        // 4*130 xh rows per tile

  const char* w1tB = (const char*)w1t + (long)ocT * 65536;
  const char* xhB  = (const char*)xh;

  const int srow = lane >> 2;                               // 16 rows/unit
  const int schk = ((lane & 3) ^ ((lane >> 3) & 3)) << 4;   // src chunk swizzle
  const int si   = wave - 4;                                // stager idx 0..3

  // stage the 4KB A tile of (tap j, col ck): stager si writes rows si*16..+15
  auto stageA = [&](int ck, int j) {
    const char* src = w1tB + (long)j * 524288 +
                      (long)(si * 16 + srow) * 1024 + ck * 64 + schk;
    gload16(src, Ab + j * 4096 + si * 1024);
  };
  // stage 1KB unit u (16 xh rows) of the B window at column ck
  auto stageB = [&](int ck, int u, char* Bt) {
    const char* src = xhB + (rbase + u * 16 + srow) * 1024 + ck * 64 + schk;
    gload16(src, Bt + u * 1024);
  };

  // compute wave cw owns px [cw*128, cw*128+128): local B row base
  const int cw    = wave;                 // valid for waves 0-3
  const int cwrow = cw * 130 + l15;
  const int aoff  = l15 * 64 + ((quad ^ ((l15 >> 1) & 3)) << 4);

  f32x4 acc[4][8];
#pragma unroll
  for (int i = 0; i < 4; ++i)
#pragma unroll
    for (int k = 0; k < 8; ++k) acc[i][k] = (f32x4){0.f, 0.f, 0.f, 0.f};

  // fragment sets: 2 A (ax, ay), 3 B (b0, b1, b2) -- 2-deep rotation
  bf16x8 ax0, ax1, ax2, ax3, ay0, ay1, ay2, ay3;
  bf16x8 b00, b01, b02, b03, b10, b11, b12, b13, b20, b21, b22, b23;

#define BROW(R, BT) (*(const bf16x8*)((BT) + (R) * 64 + ((quad ^ (((R) >> 1) & 3)) << 4)))
#define READ_A4(A0, A1, A2, A3, TAP)                                          \
  do {                                                                        \
    const char* _ab = Ab + (TAP) * 4096 + aoff;                               \
    A0 = *(const bf16x8*)(_ab);                                               \
    A1 = *(const bf16x8*)(_ab + 1024);                                        \
    A2 = *(const bf16x8*)(_ab + 2048);                                        \
    A3 = *(const bf16x8*)(_ab + 3072);                                        \
  } while (0)
#define READ_B4(B0, B1, B2, B3, KO, HOFF, BT)                                 \
  do {                                                                        \
    const int _r0 = cwrow + (HOFF) + (KO);                                    \
    B0 = BROW(_r0, BT);                                                       \
    B1 = BROW(_r0 + 16, BT);                                                  \
    B2 = BROW(_r0 + 32, BT);                                                  \
    B3 = BROW(_r0 + 48, BT);                                                  \
  } while (0)
#define MF2(MI, CJ, AF, BF)                                                   \
  acc[MI][CJ] = __builtin_amdgcn_mfma_f32_16x16x32_bf16(AF, BF, acc[MI][CJ], 0, 0, 0)
#define MFMAH(A0, A1, A2, A3, B0, B1, B2, B3, C)                              \
  do {                                                                        \
    __builtin_amdgcn_s_setprio(1);                                            \
    MF2(0, (C) + 0, A0, B0); MF2(0, (C) + 1, A0, B1);                         \
    MF2(0, (C) + 2, A0, B2); MF2(0, (C) + 3, A0, B3);                         \
    MF2(1, (C) + 0, A1, B0); MF2(1, (C) + 1, A1, B1);                         \
    MF2(1, (C) + 2, A1, B2); MF2(1, (C) + 3, A1, B3);                         \
    MF2(2, (C) + 0, A2, B0); MF2(2, (C) + 1, A2, B1);                         \
    MF2(2, (C) + 2, A2, B2); MF2(2, (C) + 3, A2, B3);                         \
    MF2(3, (C) + 0, A3, B0); MF2(3, (C) + 1, A3, B1);                         \
    MF2(3, (C) + 2, A3, B2); MF2(3, (C) + 3, A3, B3);                         \
    __builtin_amdgcn_s_setprio(0);                                            \
  } while (0)

#define WAIT0  asm volatile("s_waitcnt vmcnt(0)" ::: "memory")
#define WAIT3  asm volatile("s_waitcnt vmcnt(3)" ::: "memory")
#define WAIT7  asm volatile("s_waitcnt vmcnt(7)" ::: "memory")
#define BARR   __builtin_amdgcn_s_barrier()
#define SB     __builtin_amdgcn_sched_barrier(0)

  // prologue: stagers load B(0) fully + A taps 0-5 of ck0 (groups 0,1)
  if (wave >= 4) {
    const int u0 = (si == 0) ? 0 : 13 + (si - 1) * 12;
    const int n  = (si == 0) ? 13 : 12;
    for (int u = 0; u < n; ++u) stageB(0, u0 + u, Bb0);
#pragma unroll
    for (int j = 0; j < 6; ++j) stageA(0, j);
  }

  // 48 groups of 3 subslots; group g = (s, q): taps q*3..q*3+2 of ck s
  int s = 0, q = 0;
#pragma unroll 1
  for (int g = 0; g < 48; ++g) {
    if (wave >= 4) {
      if (g == 0 || g == 47) { WAIT0; }
      else if (q == 0 || g == 46) { WAIT3; }
      else { WAIT7; }
    }
    BARR;
    char* Bcur = (s & 1) ? Bb1 : Bb0;
    char* Bnxt = (s & 1) ? Bb0 : Bb1;
    if (wave >= 4) {
      // B first, then A (queue order makes the counted waits certify right)
      if (s < 15) {
        const int n  = (si == 0 && q == 0) ? 5 : 4;
        const int u0 = (si == 0) ? ((q == 0) ? 0 : 5 + (q - 1) * 4)
                                 : (13 + (si - 1) * 12 + q * 4);
        for (int u = 0; u < n; ++u) stageB(s + 1, u0 + u, Bnxt);
      }
      if (g <= 45) {                    // stage A(g+2): 3 taps, 1KB each
        const int ss = s + ((q >= 1) ? 1 : 0);
        const int jb = ((q + 2) % 3) * 3;
        stageA(ss, jb); stageA(ss, jb + 1); stageA(ss, jb + 2);
      }
    } else {
      // ---- compute group: 6 halves, 2-deep read pipeline ----
      const int j0 = q * 3;
      const int kb = q * 130;
      // fill: r(h0), r(h1)
      READ_A4(ax0, ax1, ax2, ax3, j0);
      READ_B4(b00, b01, b02, b03, kb + 0, 0, Bcur);
      READ_B4(b10, b11, b12, b13, kb + 0, 64, Bcur);
      SB;
      // h0: issue r(h2), MFMA(h0)
      READ_A4(ay0, ay1, ay2, ay3, j0 + 1);
      READ_B4(b20, b21, b22, b23, kb + 1, 0, Bcur);
      SB;
      MFMAH(ax0, ax1, ax2, ax3, b00, b01, b02, b03, 0);
      // h1: issue r(h3), MFMA(h1)
      READ_B4(b00, b01, b02, b03, kb + 1, 64, Bcur);
      SB;
      MFMAH(ax0, ax1, ax2, ax3, b10, b11, b12, b13, 4);
      // h2: issue r(h4), MFMA(h2)
      READ_A4(ax0, ax1, ax2, ax3, j0 + 2);
      READ_B4(b10, b11, b12, b13, kb + 2, 0, Bcur);
      SB;
      MFMAH(ay0, ay1, ay2, ay3, b20, b21, b22, b23, 0);
      // h3: issue r(h5), MFMA(h3)
      READ_B4(b20, b21, b22, b23, kb + 2, 64, Bcur);
      SB;
      MFMAH(ay0, ay1, ay2, ay3, b00, b01, b02, b03, 4);
      // h4
      SB;
      MFMAH(ax0, ax1, ax2, ax3, b10, b11, b12, b13, 0);
      // h5
      SB;
      MFMAH(ax0, ax1, ax2, ax3, b20, b21, b22, b23, 4);
    }
    ++q; if (q == 3) { q = 0; ++s; }
  }

#undef WAIT0
#undef WAIT3
#undef WAIT7
#undef BARR
#undef SB
#undef BROW
#undef READ_A4
#undef READ_B4
#undef MF2
#undef MFMAH

  if (wave >= 4) return;               // stagers done

  // epilogue: bias + relu, store bf16 NHWC mid[px][oc]
#pragma unroll
  for (int mi = 0; mi < 4; ++mi) {
    const int oc = ocT * 64 + mi * 16 + quad * 4;
    const float bv0 = b1[oc], bv1 = b1[oc + 1], bv2 = b1[oc + 2], bv3 = b1[oc + 3];
#pragma unroll
    for (int ni = 0; ni < 8; ++ni) {
      const int gpx = (r4 * 4 + cw) * 128 + ni * 16 + l15;
      f32x4 a = acc[mi][ni];
      float t0 = a[0] + bv0; t0 = t0 > 0.f ? t0 : 0.f;
      float t1 = a[1] + bv1; t1 = t1 > 0.f ? t1 : 0.f;
      float t2 = a[2] + bv2; t2 = t2 > 0.f ? t2 : 0.f;
      float t3 = a[3] + bv3; t3 = t3 > 0.f ? t3 : 0.f;
      bf16x4 v = {(bf16)t0, (bf16)t1, (bf16)t2, (bf16)t3};
      *(bf16x4*)(mid + (long)gpx * 512 + oc) = v;
    }
  }
}

// ---------------- head: barrier-free K-split GEMM + anchor decode ----------
__global__ __launch_bounds__(256) void head_gemm(
    const bf16* __restrict__ w2p, const bf16* __restrict__ mid,
    const float* __restrict__ loc_b, const float* __restrict__ score_b,
    float* __restrict__ out) {
  __shared__ f32x4 red[3][64][5];
  const int tid  = threadIdx.x;
  const int wave = tid >> 6;
  const int lane = tid & 63;
  const int quad = lane >> 4;
  const int l15  = lane & 15;
  const int px0  = blockIdx.x * 16;
  const bf16* mB = mid + (long)px0 * 512;

  f32x4 acc[5];
#pragma unroll
  for (int i = 0; i < 5; ++i) acc[i] = (f32x4){0.f, 0.f, 0.f, 0.f};

#pragma unroll
  for (int st = 0; st < 4; ++st) {
    const int k0 = wave * 128 + st * 32;
    bf16x8 bfr = *(const bf16x8*)(mB + (long)l15 * 512 + k0 + quad * 8);
#pragma unroll
    for (int mi = 0; mi < 5; ++mi) {
      bf16x8 af = *(const bf16x8*)(w2p + (long)(mi * 16 + l15) * 512 + k0 + quad * 8);
      acc[mi] = __builtin_amdgcn_mfma_f32_16x16x32_bf16(af, bfr, acc[mi], 0, 0, 0);
    }
  }

  if (wave > 0) {
#pragma unroll
    for (int mi = 0; mi < 5; ++mi) red[wave - 1][lane][mi] = acc[mi];
  }
  __syncthreads();
  if (wave != 0) return;
#pragma unroll
  for (int w = 0; w < 3; ++w)
#pragma unroll
    for (int mi = 0; mi < 5; ++mi) acc[mi] += red[w][lane][mi];

  const int p    = px0 + l15;
  const int hh   = p >> 7;
  const int wcol = p & 127;
  const float cx = 16.f * (float)hh;
  const float cy = 16.f * (float)wcol;
  const float s0 = quad == 0 ? 45.f : quad == 1 ? 91.f : quad == 2 ? 181.f : 362.f;
  const float s1 = quad == 0 ? 32.f : quad == 1 ? 64.f : quad == 2 ? 128.f : 256.f;
  const float s2 = quad == 0 ? 23.f : quad == 1 ? 45.f : quad == 2 ? 91.f : 181.f;
  const float aw[3] = {s0, s1, s2};
  const float ah[3] = {s2, s1, s0};
#pragma unroll
  for (int mi = 0; mi < 5; ++mi) {
#pragma unroll
    for (int r = 0; r < 4; ++r) {
      const int oc2 = mi * 16 + quad * 4 + r;
      float v = acc[mi][r];
      if (mi < 3) {
        v += loc_b[oc2];
        out[p * 48 + oc2] = v;
        float roi;
        if (r == 0)      roi = v * aw[mi] + cx;
        else if (r == 1) roi = v * ah[mi] + cy;
        else if (r == 2) roi = __expf(v) * aw[mi];
        else             roi = __expf(v) * ah[mi];
        out[OUT_ROI + p * 48 + oc2] = roi;
      } else {
        const int sc = oc2 - 48;
        if (sc < 24) {
          v += score_b[sc];
          out[OUT_CLS + p * 24 + sc] = v;
        }
      }
    }
  }
}

// ---------------------------------------------------------------------------
extern "C" void kernel_launch(void* const* d_in, const int* in_sizes, int n_in,
                              void* d_out, int out_size, void* d_ws, size_t ws_size,
                              hipStream_t stream) {
  (void)in_sizes; (void)n_in; (void)out_size; (void)ws_size;
  const float* x       = (const float*)d_in[0];
  const float* conv1_w = (const float*)d_in[1];
  const float* conv1_b = (const float*)d_in[2];
  const float* score_w = (const float*)d_in[3];
  const float* score_b = (const float*)d_in[4];
  const float* loc_w   = (const float*)d_in[5];
  const float* loc_b   = (const float*)d_in[6];
  char* ws = (char*)d_ws;
  bf16* xh  = (bf16*)(ws + WS_XH);
  bf16* w1t = (bf16*)(ws + WS_W1T);
  bf16* w2p = (bf16*)(ws + WS_W2P);
  bf16* mid = (bf16*)(ws + WS_MID);
  float* out = (float*)d_out;

  static int attr_done = 0;
  if (!attr_done) {
    (void)hipFuncSetAttribute((const void*)conv1_gemm,
                              hipFuncAttributeMaxDynamicSharedMemorySize, 137216);
    attr_done = 1;
  }

  hipLaunchKernelGGL(prep_all,   dim3(3364), dim3(256), 0, stream,
                     (int4*)xh, conv1_w, w1t, loc_w, score_w, w2p, x, xh);
  hipLaunchKernelGGL(conv1_gemm, dim3(256),  dim3(512), 137216, stream,
                     w1t, xh, conv1_b, mid);
  hipLaunchKernelGGL(head_gemm,  dim3(1024), dim3(256), 0, stream,
                     w2p, mid, loc_b, score_b, out);
}